// Round 5
// baseline (455.480 us; speedup 1.0000x reference)
//
#include <hip/hip_runtime.h>
#include <hip/hip_bf16.h>
#include <stdint.h>

#define NUM_MODALS 4
#define SHARED_IDX 3

typedef __attribute__((ext_vector_type(8))) short bf16x8;
typedef __attribute__((ext_vector_type(4))) float floatx4;

__device__ __forceinline__ unsigned short f2bf(float f) {
  unsigned int u = __float_as_uint(f);
  u += 0x7fffu + ((u >> 16) & 1u);   // round-to-nearest-even
  return (unsigned short)(u >> 16);
}

// ---------------- W_eff build (round-0 proven version) ----------------
// W_eff[m][o][c] = Wp[o][c] + sum_r Bw[3][o][r]*A[3][r][c] + sum_r Bw[m][o][r]*A[m][r][c]
__global__ __launch_bounds__(256) void weff_fast(
    const float* __restrict__ Wp, const float* __restrict__ A,
    const float* __restrict__ Bw, unsigned short* __restrict__ Weff) {
  const int c  = blockIdx.x * 256 + threadIdx.x;
  const int o0 = blockIdx.y * 16;
  const int m  = blockIdx.z;

  __shared__ float b3[256], bm[256];   // 16 o-rows x 16 r, both adapters
  const int t = threadIdx.x;
  {
    const int o = o0 + (t >> 4);
    const int r = t & 15;
    b3[t] = Bw[(SHARED_IDX * 768 + o) * 16 + r];
    bm[t] = Bw[((size_t)m * 768 + o) * 16 + r];
  }
  __syncthreads();

  float a3[16], am[16];
#pragma unroll
  for (int r = 0; r < 16; ++r) {
    a3[r] = A[(SHARED_IDX * 16 + r) * 768 + c];
    am[r] = A[((size_t)m * 16 + r) * 768 + c];
  }
#pragma unroll 4
  for (int oo = 0; oo < 16; ++oo) {
    const int o = o0 + oo;
    float acc = Wp[(size_t)o * 768 + c];
#pragma unroll
    for (int r = 0; r < 16; ++r) {
      acc += b3[oo * 16 + r] * a3[r];
      acc += bm[oo * 16 + r] * am[r];
    }
    Weff[((size_t)m * 768 + o) * 768 + c] = f2bf(acc);
  }
}

// ---------------- fused GEMM: out[m] = X[m] (fp32, cvt in-reg) * Weff[m]^T + bp ----
// Round-5 = round-4 resubmitted (bench infra failed; kernel re-audited: no
// divergent barriers, vmcnt ledger closes, no spill risk).
// Round-4 change vs round-3: X prefetch deepened to DISTANCE 2. Two named
// register sets xv[0] (even kt) / xv[1] (odd kt); X(kt) is issued mid-step
// kt-2 and consumed at top of step kt — two full compute phases + barriers
// (~1500+ cy) after issue, covering loaded-system global latency (~1100-1400
// cy). W unchanged (already distance 2 via Ws double-buffer).
// VMEM queue at top of step kt (24 ops): [W(kt):4, X(kt):8, W(kt+1):4, X(kt+1):8]
//   -> s_waitcnt vmcnt(12) retires exactly {W(kt), X(kt)}. Ordering is robust:
// asm memory clobbers confine every VMEM op to its inter-wait region, so the
// oldest-12 set is invariant to intra-region scheduling. vmcnt(0) only at
// kt=11 (queue = [W11:4, X11:8] = 12 ops).
// Hazards identical to round 3: Ws[b] re-staged only after barrier-2 of the
// step that read it; As writes at step top ordered after barrier-2 of kt-1.
// LDS 48 KB -> 3 blocks/CU; launch_bounds(256,3) -> VGPR cap ~170 (need ~148).
__global__ __launch_bounds__(256, 3) void lora_gemm_fused(
    const float* __restrict__ X,
    const unsigned short* __restrict__ Weff,
    const float* __restrict__ bp,
    float* __restrict__ out) {
  const int bid = blockIdx.x;
  const int xcd = bid & 7;
  const int s   = bid >> 3;          // 0..191
  const int w   = xcd * 192 + s;     // contiguous per-XCD chunk
  const int ct  = w % 6;
  const int rt  = w / 6;             // 0..255
  const int m        = rt >> 6;
  const int row_base = (rt & 63) * 128;
  const int col_base = ct * 128;

  __shared__ alignas(16) unsigned short As[128 * 64];       // 16 KB
  __shared__ alignas(16) unsigned short Ws[2 * 128 * 64];   // 32 KB

  const int tid  = threadIdx.x;
  const int wave = tid >> 6;
  const int lane = tid & 63;
  const int ln = lane & 15;
  const int qd = lane >> 4;
  const int wm = wave & 1;
  const int wn = wave >> 1;

  const float*          Xm = X    + (size_t)m * 8192 * 768;
  const unsigned short* Wm = Weff + (size_t)m * 768 * 768;

  floatx4 acc[4][4];
#pragma unroll
  for (int i = 0; i < 4; ++i)
#pragma unroll
    for (int j = 0; j < 4; ++j)
      acc[i][j] = (floatx4)(0.0f);

  // --- X staging geometry: thread covers (row xr+p*16, 4 fp32 cols at xc) ---
  const int xr   = tid >> 4;         // 0..15
  const int xc   = (tid & 15) * 4;   // 0..60
  const int cb   = xc >> 3;          // 16B col-block 0..7
  const int half = (xc >> 2) & 1;    // which 8B half of the block
  const float* xsrc[8];
  unsigned short* xdst[8];
#pragma unroll
  for (int p = 0; p < 8; ++p) {
    const int r = xr + p * 16;
    xsrc[p] = Xm + (size_t)(row_base + r) * 768 + xc;
    xdst[p] = &As[r * 64 + (cb ^ (r & 7)) * 8 + half * 4];
  }
  // --- W staging geometry (global_load_lds: 8 rows x 128 B per issue) ---
  const int sr = lane >> 3;          // row-in-8
  const int ss = lane & 7;           // LDS slot this lane fills
  const unsigned short* wsrc[4];
#pragma unroll
  for (int p = 0; p < 4; ++p) {
    const int r = wave * 32 + p * 8 + sr;
    wsrc[p] = Wm + (size_t)(col_base + r) * 768 + (ss ^ (r & 7)) * 8;
  }

  // ---- prologue: issue W(0)->Ws[0], X(0)->xv[0], W(1)->Ws[1], X(1)->xv[1] ----
  float4 xv[2][8];
#pragma unroll
  for (int p = 0; p < 4; ++p) {
    __builtin_amdgcn_global_load_lds(
        (const __attribute__((address_space(1))) void*)wsrc[p],
        (__attribute__((address_space(3))) void*)&Ws[(wave * 32 + p * 8) * 64],
        16, 0, 0);
    wsrc[p] += 64;
  }
#pragma unroll
  for (int p = 0; p < 8; ++p) {
    xv[0][p] = *(const float4*)xsrc[p];
    xsrc[p] += 64;
  }
#pragma unroll
  for (int p = 0; p < 4; ++p) {
    __builtin_amdgcn_global_load_lds(
        (const __attribute__((address_space(1))) void*)wsrc[p],
        (__attribute__((address_space(3))) void*)&Ws[128 * 64 + (wave * 32 + p * 8) * 64],
        16, 0, 0);
    wsrc[p] += 64;
  }
#pragma unroll
  for (int p = 0; p < 8; ++p) {
    xv[1][p] = *(const float4*)xsrc[p];
    xsrc[p] += 64;
  }

  for (int kt2 = 0; kt2 < 6; ++kt2) {
    const bool pf = (kt2 < 5);

    // ================= even step: kt = 2*kt2, Ws buffer 0, xv[0] =================
    asm volatile("s_waitcnt vmcnt(12)" ::: "memory");   // retire W(kt), X(kt)
#pragma unroll
    for (int p = 0; p < 8; ++p) {
      const float4 v = xv[0][p];
      __hip_bfloat162 h0 = __float22bfloat162_rn(make_float2(v.x, v.y));
      __hip_bfloat162 h1 = __float22bfloat162_rn(make_float2(v.z, v.w));
      uint2 hv;
      hv.x = *(unsigned int*)&h0;
      hv.y = *(unsigned int*)&h1;
      *(uint2*)xdst[p] = hv;
    }
    if (pf) {                                           // issue X(kt+2) -> xv[0]
#pragma unroll
      for (int p = 0; p < 8; ++p) {
        xv[0][p] = *(const float4*)xsrc[p];
        xsrc[p] += 64;
      }
    }
    asm volatile("s_waitcnt lgkmcnt(0)" ::: "memory");
    __builtin_amdgcn_sched_barrier(0);
    __builtin_amdgcn_s_barrier();
    __builtin_amdgcn_sched_barrier(0);

    __builtin_amdgcn_s_setprio(1);
#pragma unroll
    for (int kk = 0; kk < 64; kk += 32) {
      const int kblk = (kk >> 3) + qd;
      const int slot = (kblk ^ (ln & 7)) * 8;
      bf16x8 a[4], b[4];
#pragma unroll
      for (int i = 0; i < 4; ++i)
        a[i] = *(const bf16x8*)(&As[(wm * 64 + i * 16 + ln) * 64 + slot]);
#pragma unroll
      for (int j = 0; j < 4; ++j)
        b[j] = *(const bf16x8*)(&Ws[(wn * 64 + j * 16 + ln) * 64 + slot]);
#pragma unroll
      for (int i = 0; i < 4; ++i)
#pragma unroll
        for (int j = 0; j < 4; ++j)
          acc[i][j] = __builtin_amdgcn_mfma_f32_16x16x32_bf16(a[i], b[j], acc[i][j], 0, 0, 0);
    }
    __builtin_amdgcn_s_setprio(0);

    __builtin_amdgcn_sched_barrier(0);
    __builtin_amdgcn_s_barrier();
    __builtin_amdgcn_sched_barrier(0);

    if (pf) {                                           // issue W(kt+2) -> Ws[0]
#pragma unroll
      for (int p = 0; p < 4; ++p) {
        __builtin_amdgcn_global_load_lds(
            (const __attribute__((address_space(1))) void*)wsrc[p],
            (__attribute__((address_space(3))) void*)&Ws[(wave * 32 + p * 8) * 64],
            16, 0, 0);
        wsrc[p] += 64;
      }
    }

    // ================= odd step: kt = 2*kt2+1, Ws buffer 1, xv[1] =================
    if (pf) {
      asm volatile("s_waitcnt vmcnt(12)" ::: "memory"); // retire W(kt), X(kt)
    } else {
      asm volatile("s_waitcnt vmcnt(0)" ::: "memory");  // kt=11: drain the rest
    }
#pragma unroll
    for (int p = 0; p < 8; ++p) {
      const float4 v = xv[1][p];
      __hip_bfloat162 h0 = __float22bfloat162_rn(make_float2(v.x, v.y));
      __hip_bfloat162 h1 = __float22bfloat162_rn(make_float2(v.z, v.w));
      uint2 hv;
      hv.x = *(unsigned int*)&h0;
      hv.y = *(unsigned int*)&h1;
      *(uint2*)xdst[p] = hv;
    }
    if (pf) {                                           // issue X(kt+2) -> xv[1]
#pragma unroll
      for (int p = 0; p < 8; ++p) {
        xv[1][p] = *(const float4*)xsrc[p];
        xsrc[p] += 64;
      }
    }
    asm volatile("s_waitcnt lgkmcnt(0)" ::: "memory");
    __builtin_amdgcn_sched_barrier(0);
    __builtin_amdgcn_s_barrier();
    __builtin_amdgcn_sched_barrier(0);

    __builtin_amdgcn_s_setprio(1);
#pragma unroll
    for (int kk = 0; kk < 64; kk += 32) {
      const int kblk = (kk >> 3) + qd;
      const int slot = (kblk ^ (ln & 7)) * 8;
      bf16x8 a[4], b[4];
#pragma unroll
      for (int i = 0; i < 4; ++i)
        a[i] = *(const bf16x8*)(&As[(wm * 64 + i * 16 + ln) * 64 + slot]);
#pragma unroll
      for (int j = 0; j < 4; ++j)
        b[j] = *(const bf16x8*)(&Ws[128 * 64 + (wn * 64 + j * 16 + ln) * 64 + slot]);
#pragma unroll
      for (int i = 0; i < 4; ++i)
#pragma unroll
        for (int j = 0; j < 4; ++j)
          acc[i][j] = __builtin_amdgcn_mfma_f32_16x16x32_bf16(a[i], b[j], acc[i][j], 0, 0, 0);
    }
    __builtin_amdgcn_s_setprio(0);

    __builtin_amdgcn_sched_barrier(0);
    __builtin_amdgcn_s_barrier();
    __builtin_amdgcn_sched_barrier(0);

    if (pf) {                                           // issue W(kt+2) -> Ws[1]
#pragma unroll
      for (int p = 0; p < 4; ++p) {
        __builtin_amdgcn_global_load_lds(
            (const __attribute__((address_space(1))) void*)wsrc[p],
            (__attribute__((address_space(3))) void*)&Ws[128 * 64 + (wave * 32 + p * 8) * 64],
            16, 0, 0);
        wsrc[p] += 64;
      }
    }
  }

  float* Om = out + (size_t)m * 8192 * 768;
#pragma unroll
  for (int j = 0; j < 4; ++j) {
    const int o = col_base + wn * 64 + j * 16 + ln;
    const float bias = bp[o];
#pragma unroll
    for (int i = 0; i < 4; ++i) {
      const int R = row_base + wm * 64 + i * 16 + qd * 4;
      float* dst = Om + (size_t)R * 768 + o;
#pragma unroll
      for (int v = 0; v < 4; ++v)
        dst[(size_t)v * 768] = acc[i][j][v] + bias;
    }
  }
}

extern "C" void kernel_launch(void* const* d_in, const int* in_sizes, int n_in,
                              void* d_out, int out_size, void* d_ws, size_t ws_size,
                              hipStream_t stream) {
  const float* x  = (const float*)d_in[0];   // [32, 1024, 768]
  const float* Wp = (const float*)d_in[1];   // [768, 768]
  const float* bp = (const float*)d_in[2];   // [768]
  const float* A  = (const float*)d_in[3];   // [4, 16, 768]
  const float* Bw = (const float*)d_in[4];   // [4, 768, 16]
  float* out = (float*)d_out;                // [32, 1024, 768]

  unsigned short* Weff = (unsigned short*)d_ws;  // [4][768][768] bf16 = 4.5 MB

  weff_fast<<<dim3(3, 48, 4), 256, 0, stream>>>(Wp, A, Bw, Weff);
  lora_gemm_fused<<<dim3(1536), 256, 0, stream>>>(x, Weff, bp, out);
}

// Round 6
// 227.380 us; speedup vs baseline: 2.0032x; 2.0032x over previous
//
#include <hip/hip_runtime.h>
#include <hip/hip_bf16.h>
#include <stdint.h>

#define NUM_MODALS 4
#define SHARED_IDX 3

typedef __attribute__((ext_vector_type(8))) short bf16x8;
typedef __attribute__((ext_vector_type(4))) float floatx4;

__device__ __forceinline__ unsigned short f2bf(float f) {
  unsigned int u = __float_as_uint(f);
  u += 0x7fffu + ((u >> 16) & 1u);   // round-to-nearest-even
  return (unsigned short)(u >> 16);
}

// ---------------- W_eff build (round-0 proven version) ----------------
// W_eff[m][o][c] = Wp[o][c] + sum_r Bw[3][o][r]*A[3][r][c] + sum_r Bw[m][o][r]*A[m][r][c]
__global__ __launch_bounds__(256) void weff_fast(
    const float* __restrict__ Wp, const float* __restrict__ A,
    const float* __restrict__ Bw, unsigned short* __restrict__ Weff) {
  const int c  = blockIdx.x * 256 + threadIdx.x;
  const int o0 = blockIdx.y * 16;
  const int m  = blockIdx.z;

  __shared__ float b3[256], bm[256];   // 16 o-rows x 16 r, both adapters
  const int t = threadIdx.x;
  {
    const int o = o0 + (t >> 4);
    const int r = t & 15;
    b3[t] = Bw[(SHARED_IDX * 768 + o) * 16 + r];
    bm[t] = Bw[((size_t)m * 768 + o) * 16 + r];
  }
  __syncthreads();

  float a3[16], am[16];
#pragma unroll
  for (int r = 0; r < 16; ++r) {
    a3[r] = A[(SHARED_IDX * 16 + r) * 768 + c];
    am[r] = A[((size_t)m * 16 + r) * 768 + c];
  }
#pragma unroll 4
  for (int oo = 0; oo < 16; ++oo) {
    const int o = o0 + oo;
    float acc = Wp[(size_t)o * 768 + c];
#pragma unroll
    for (int r = 0; r < 16; ++r) {
      acc += b3[oo * 16 + r] * a3[r];
      acc += bm[oo * 16 + r] * am[r];
    }
    Weff[((size_t)m * 768 + o) * 768 + c] = f2bf(acc);
  }
}

// ---------------- fused GEMM: out[m] = X[m] (fp32, cvt in-reg) * Weff[m]^T + bp ----
// Round-6 = round-5 minus the __launch_bounds__(256,3) occupancy promise.
// ROUND-5 POST-MORTEM: the ",3" capped the UNIFIED VGPR+AGPR budget at ~170;
// acc[4][4] = 64 AGPRs count against it, leaving ~106 arch VGPRs — the
// allocator spilled xv[2][8] to scratch (VGPR_Count fell 116->84 and
// FETCH/WRITE grew by ~746 MB = 393k threads round-tripping the 128 B
// prefetch set x12 steps). Plain launch_bounds(256): LDS (48 KB) already caps
// residency at 3 blocks/CU, so the promise bought nothing.
// Pipeline (unchanged from round 5): X prefetch DISTANCE 2 via two named
// register sets xv[0]/xv[1]; W distance 2 via Ws double-buffer; counted
// s_waitcnt vmcnt(12) (queue 24: [W(kt):4, X(kt):8, W(kt+1):4, X(kt+1):8]);
// raw s_barrier; vmcnt(0) only at kt=11. Hazards as round 3.
__global__ __launch_bounds__(256) void lora_gemm_fused(
    const float* __restrict__ X,
    const unsigned short* __restrict__ Weff,
    const float* __restrict__ bp,
    float* __restrict__ out) {
  const int bid = blockIdx.x;
  const int xcd = bid & 7;
  const int s   = bid >> 3;          // 0..191
  const int w   = xcd * 192 + s;     // contiguous per-XCD chunk
  const int ct  = w % 6;
  const int rt  = w / 6;             // 0..255
  const int m        = rt >> 6;
  const int row_base = (rt & 63) * 128;
  const int col_base = ct * 128;

  __shared__ alignas(16) unsigned short As[128 * 64];       // 16 KB
  __shared__ alignas(16) unsigned short Ws[2 * 128 * 64];   // 32 KB

  const int tid  = threadIdx.x;
  const int wave = tid >> 6;
  const int lane = tid & 63;
  const int ln = lane & 15;
  const int qd = lane >> 4;
  const int wm = wave & 1;
  const int wn = wave >> 1;

  const float*          Xm = X    + (size_t)m * 8192 * 768;
  const unsigned short* Wm = Weff + (size_t)m * 768 * 768;

  floatx4 acc[4][4];
#pragma unroll
  for (int i = 0; i < 4; ++i)
#pragma unroll
    for (int j = 0; j < 4; ++j)
      acc[i][j] = (floatx4)(0.0f);

  // --- X staging geometry: thread covers (row xr+p*16, 4 fp32 cols at xc) ---
  const int xr   = tid >> 4;         // 0..15
  const int xc   = (tid & 15) * 4;   // 0..60
  const int cb   = xc >> 3;          // 16B col-block 0..7
  const int half = (xc >> 2) & 1;    // which 8B half of the block
  const float* xsrc[8];
  unsigned short* xdst[8];
#pragma unroll
  for (int p = 0; p < 8; ++p) {
    const int r = xr + p * 16;
    xsrc[p] = Xm + (size_t)(row_base + r) * 768 + xc;
    xdst[p] = &As[r * 64 + (cb ^ (r & 7)) * 8 + half * 4];
  }
  // --- W staging geometry (global_load_lds: 8 rows x 128 B per issue) ---
  const int sr = lane >> 3;          // row-in-8
  const int ss = lane & 7;           // LDS slot this lane fills
  const unsigned short* wsrc[4];
#pragma unroll
  for (int p = 0; p < 4; ++p) {
    const int r = wave * 32 + p * 8 + sr;
    wsrc[p] = Wm + (size_t)(col_base + r) * 768 + (ss ^ (r & 7)) * 8;
  }

  // ---- prologue: issue W(0)->Ws[0], X(0)->xv[0], W(1)->Ws[1], X(1)->xv[1] ----
  float4 xv[2][8];
#pragma unroll
  for (int p = 0; p < 4; ++p) {
    __builtin_amdgcn_global_load_lds(
        (const __attribute__((address_space(1))) void*)wsrc[p],
        (__attribute__((address_space(3))) void*)&Ws[(wave * 32 + p * 8) * 64],
        16, 0, 0);
    wsrc[p] += 64;
  }
#pragma unroll
  for (int p = 0; p < 8; ++p) {
    xv[0][p] = *(const float4*)xsrc[p];
    xsrc[p] += 64;
  }
#pragma unroll
  for (int p = 0; p < 4; ++p) {
    __builtin_amdgcn_global_load_lds(
        (const __attribute__((address_space(1))) void*)wsrc[p],
        (__attribute__((address_space(3))) void*)&Ws[128 * 64 + (wave * 32 + p * 8) * 64],
        16, 0, 0);
    wsrc[p] += 64;
  }
#pragma unroll
  for (int p = 0; p < 8; ++p) {
    xv[1][p] = *(const float4*)xsrc[p];
    xsrc[p] += 64;
  }

  for (int kt2 = 0; kt2 < 6; ++kt2) {
    const bool pf = (kt2 < 5);

    // ================= even step: kt = 2*kt2, Ws buffer 0, xv[0] =================
    asm volatile("s_waitcnt vmcnt(12)" ::: "memory");   // retire W(kt), X(kt)
#pragma unroll
    for (int p = 0; p < 8; ++p) {
      const float4 v = xv[0][p];
      __hip_bfloat162 h0 = __float22bfloat162_rn(make_float2(v.x, v.y));
      __hip_bfloat162 h1 = __float22bfloat162_rn(make_float2(v.z, v.w));
      uint2 hv;
      hv.x = *(unsigned int*)&h0;
      hv.y = *(unsigned int*)&h1;
      *(uint2*)xdst[p] = hv;
    }
    if (pf) {                                           // issue X(kt+2) -> xv[0]
#pragma unroll
      for (int p = 0; p < 8; ++p) {
        xv[0][p] = *(const float4*)xsrc[p];
        xsrc[p] += 64;
      }
    }
    asm volatile("s_waitcnt lgkmcnt(0)" ::: "memory");
    __builtin_amdgcn_sched_barrier(0);
    __builtin_amdgcn_s_barrier();
    __builtin_amdgcn_sched_barrier(0);

    __builtin_amdgcn_s_setprio(1);
#pragma unroll
    for (int kk = 0; kk < 64; kk += 32) {
      const int kblk = (kk >> 3) + qd;
      const int slot = (kblk ^ (ln & 7)) * 8;
      bf16x8 a[4], b[4];
#pragma unroll
      for (int i = 0; i < 4; ++i)
        a[i] = *(const bf16x8*)(&As[(wm * 64 + i * 16 + ln) * 64 + slot]);
#pragma unroll
      for (int j = 0; j < 4; ++j)
        b[j] = *(const bf16x8*)(&Ws[(wn * 64 + j * 16 + ln) * 64 + slot]);
#pragma unroll
      for (int i = 0; i < 4; ++i)
#pragma unroll
        for (int j = 0; j < 4; ++j)
          acc[i][j] = __builtin_amdgcn_mfma_f32_16x16x32_bf16(a[i], b[j], acc[i][j], 0, 0, 0);
    }
    __builtin_amdgcn_s_setprio(0);

    __builtin_amdgcn_sched_barrier(0);
    __builtin_amdgcn_s_barrier();
    __builtin_amdgcn_sched_barrier(0);

    if (pf) {                                           // issue W(kt+2) -> Ws[0]
#pragma unroll
      for (int p = 0; p < 4; ++p) {
        __builtin_amdgcn_global_load_lds(
            (const __attribute__((address_space(1))) void*)wsrc[p],
            (__attribute__((address_space(3))) void*)&Ws[(wave * 32 + p * 8) * 64],
            16, 0, 0);
        wsrc[p] += 64;
      }
    }

    // ================= odd step: kt = 2*kt2+1, Ws buffer 1, xv[1] =================
    if (pf) {
      asm volatile("s_waitcnt vmcnt(12)" ::: "memory"); // retire W(kt), X(kt)
    } else {
      asm volatile("s_waitcnt vmcnt(0)" ::: "memory");  // kt=11: drain the rest
    }
#pragma unroll
    for (int p = 0; p < 8; ++p) {
      const float4 v = xv[1][p];
      __hip_bfloat162 h0 = __float22bfloat162_rn(make_float2(v.x, v.y));
      __hip_bfloat162 h1 = __float22bfloat162_rn(make_float2(v.z, v.w));
      uint2 hv;
      hv.x = *(unsigned int*)&h0;
      hv.y = *(unsigned int*)&h1;
      *(uint2*)xdst[p] = hv;
    }
    if (pf) {                                           // issue X(kt+2) -> xv[1]
#pragma unroll
      for (int p = 0; p < 8; ++p) {
        xv[1][p] = *(const float4*)xsrc[p];
        xsrc[p] += 64;
      }
    }
    asm volatile("s_waitcnt lgkmcnt(0)" ::: "memory");
    __builtin_amdgcn_sched_barrier(0);
    __builtin_amdgcn_s_barrier();
    __builtin_amdgcn_sched_barrier(0);

    __builtin_amdgcn_s_setprio(1);
#pragma unroll
    for (int kk = 0; kk < 64; kk += 32) {
      const int kblk = (kk >> 3) + qd;
      const int slot = (kblk ^ (ln & 7)) * 8;
      bf16x8 a[4], b[4];
#pragma unroll
      for (int i = 0; i < 4; ++i)
        a[i] = *(const bf16x8*)(&As[(wm * 64 + i * 16 + ln) * 64 + slot]);
#pragma unroll
      for (int j = 0; j < 4; ++j)
        b[j] = *(const bf16x8*)(&Ws[128 * 64 + (wn * 64 + j * 16 + ln) * 64 + slot]);
#pragma unroll
      for (int i = 0; i < 4; ++i)
#pragma unroll
        for (int j = 0; j < 4; ++j)
          acc[i][j] = __builtin_amdgcn_mfma_f32_16x16x32_bf16(a[i], b[j], acc[i][j], 0, 0, 0);
    }
    __builtin_amdgcn_s_setprio(0);

    __builtin_amdgcn_sched_barrier(0);
    __builtin_amdgcn_s_barrier();
    __builtin_amdgcn_sched_barrier(0);

    if (pf) {                                           // issue W(kt+2) -> Ws[1]
#pragma unroll
      for (int p = 0; p < 4; ++p) {
        __builtin_amdgcn_global_load_lds(
            (const __attribute__((address_space(1))) void*)wsrc[p],
            (__attribute__((address_space(3))) void*)&Ws[128 * 64 + (wave * 32 + p * 8) * 64],
            16, 0, 0);
        wsrc[p] += 64;
      }
    }
  }

  float* Om = out + (size_t)m * 8192 * 768;
#pragma unroll
  for (int j = 0; j < 4; ++j) {
    const int o = col_base + wn * 64 + j * 16 + ln;
    const float bias = bp[o];
#pragma unroll
    for (int i = 0; i < 4; ++i) {
      const int R = row_base + wm * 64 + i * 16 + qd * 4;
      float* dst = Om + (size_t)R * 768 + o;
#pragma unroll
      for (int v = 0; v < 4; ++v)
        dst[(size_t)v * 768] = acc[i][j][v] + bias;
    }
  }
}

extern "C" void kernel_launch(void* const* d_in, const int* in_sizes, int n_in,
                              void* d_out, int out_size, void* d_ws, size_t ws_size,
                              hipStream_t stream) {
  const float* x  = (const float*)d_in[0];   // [32, 1024, 768]
  const float* Wp = (const float*)d_in[1];   // [768, 768]
  const float* bp = (const float*)d_in[2];   // [768]
  const float* A  = (const float*)d_in[3];   // [4, 16, 768]
  const float* Bw = (const float*)d_in[4];   // [4, 768, 16]
  float* out = (float*)d_out;                // [32, 1024, 768]

  unsigned short* Weff = (unsigned short*)d_ws;  // [4][768][768] bf16 = 4.5 MB

  weff_fast<<<dim3(3, 48, 4), 256, 0, stream>>>(Wp, A, Bw, Weff);
  lora_gemm_fused<<<dim3(1536), 256, 0, stream>>>(x, Weff, bp, out);
}

// Round 8
// 212.482 us; speedup vs baseline: 2.1436x; 1.0701x over previous
//
#include <hip/hip_runtime.h>
#include <hip/hip_bf16.h>
#include <stdint.h>

#define NUM_MODALS 4
#define SHARED_IDX 3

typedef __attribute__((ext_vector_type(8))) short bf16x8;
typedef __attribute__((ext_vector_type(4))) float floatx4;

__device__ __forceinline__ unsigned short f2bf(float f) {
  unsigned int u = __float_as_uint(f);
  u += 0x7fffu + ((u >> 16) & 1u);   // round-to-nearest-even
  return (unsigned short)(u >> 16);
}

// ---------------- W_eff build (round-0 proven version) ----------------
// W_eff[m][o][c] = Wp[o][c] + sum_r Bw[3][o][r]*A[3][r][c] + sum_r Bw[m][o][r]*A[m][r][c]
__global__ __launch_bounds__(256) void weff_fast(
    const float* __restrict__ Wp, const float* __restrict__ A,
    const float* __restrict__ Bw, unsigned short* __restrict__ Weff) {
  const int c  = blockIdx.x * 256 + threadIdx.x;
  const int o0 = blockIdx.y * 16;
  const int m  = blockIdx.z;

  __shared__ float b3[256], bm[256];   // 16 o-rows x 16 r, both adapters
  const int t = threadIdx.x;
  {
    const int o = o0 + (t >> 4);
    const int r = t & 15;
    b3[t] = Bw[(SHARED_IDX * 768 + o) * 16 + r];
    bm[t] = Bw[((size_t)m * 768 + o) * 16 + r];
  }
  __syncthreads();

  float a3[16], am[16];
#pragma unroll
  for (int r = 0; r < 16; ++r) {
    a3[r] = A[(SHARED_IDX * 16 + r) * 768 + c];
    am[r] = A[((size_t)m * 16 + r) * 768 + c];
  }
#pragma unroll 4
  for (int oo = 0; oo < 16; ++oo) {
    const int o = o0 + oo;
    float acc = Wp[(size_t)o * 768 + c];
#pragma unroll
    for (int r = 0; r < 16; ++r) {
      acc += b3[oo * 16 + r] * a3[r];
      acc += bm[oo * 16 + r] * am[r];
    }
    Weff[((size_t)m * 768 + o) * 768 + c] = f2bf(acc);
  }
}

// ---------------- fused GEMM: out[m] = X[m] (fp32, cvt in-reg) * Weff[m]^T + bp ----
// Round-8 = round-7 resubmitted (broker container failure, same as round 4;
// source re-audited: barriers unconditional, vmcnt ledger closes, bounds ok,
// no launch-bounds spill risk). One variable vs round 3: tile 128x128 -> 128x256.
// 128x256 tile, BK=64, 512 threads, 8 waves (2M x 4N), round-3 counted-vmcnt
// skeleton verbatim (best measured: 95 us; round-6 showed deeper X prefetch
// regresses, so X stays distance 1).
// Why: per block-kt the old tile staged 48 KB for 128 MFMAs (375 B/MFMA);
// this tile stages 64 KB for 256 MFMAs (250 B/MFMA, -33%), halves X L2
// re-reads (3 col-blocks per row-tile, not 6), halves per-thread cvt/ds_write
// serial work, and doubles MFMA per barrier interval. LDS = As 16 KB +
// Ws dbuf 64 KB = 80 KB -> 2 blocks/CU x 8 waves = 16 waves/CU (vs 12).
// No __launch_bounds__ VGPR promise (round-5 lesson: unified VGPR+AGPR file;
// acc counts against the cap -> spill). Round-2's 512-thr failure was that cap.
// vmcnt ledger (per wave, all waves identical): prologue issues W(0):4,
// X(0):4, W(1):4 -> queue 12. Top of kt: [W(kt):4, X(kt):4, W(kt+1):4] ->
// vmcnt(4) retires exactly {W(kt), X(kt)}. Mid-kt: issue X(kt+1) (kt<11).
// After bar-2: issue W(kt+2) (kt<10). kt=11: queue [W11:4, X11:4] -> vmcnt(0).
// Issue counts: X 1+11=12, W 2+10=12. Hazards: Ws[b] re-staged only after
// bar-2 of the kt that read it; As written at kt-top, ordered after bar-2 of
// kt-1; all s_barriers unconditional (pf contains no barriers).
__global__ void lora_gemm_fused(
    const float* __restrict__ X,
    const unsigned short* __restrict__ Weff,
    const float* __restrict__ bp,
    float* __restrict__ out) {
  const int bid = blockIdx.x;
  const int xcd = bid & 7;
  const int s   = bid >> 3;          // 0..95
  const int w   = xcd * 96 + s;      // contiguous per-XCD chunk
  const int ct  = w % 3;             // 3 col-tiles of 256
  const int rt  = w / 3;             // 0..255 row-tiles of 128
  const int m        = rt >> 6;      // 64 row-tiles per modality
  const int row_base = (rt & 63) * 128;
  const int col_base = ct * 256;

  __shared__ alignas(16) unsigned short As[128 * 64];       // 16 KB
  __shared__ alignas(16) unsigned short Ws[2 * 256 * 64];   // 64 KB (dbuf)

  const int tid  = threadIdx.x;      // 0..511
  const int wave = tid >> 6;         // 0..7
  const int lane = tid & 63;
  const int ln = lane & 15;
  const int qd = lane >> 4;
  const int wm = wave & 1;           // M half (2 x 64 rows)
  const int wn = wave >> 1;          // N quadrant (4 x 64 cols)

  const float*          Xm = X    + (size_t)m * 8192 * 768;
  const unsigned short* Wm = Weff + (size_t)m * 768 * 768;

  floatx4 acc[4][4];
#pragma unroll
  for (int i = 0; i < 4; ++i)
#pragma unroll
    for (int j = 0; j < 4; ++j)
      acc[i][j] = (floatx4)(0.0f);

  // --- X staging: thread covers (row xr+p*32, 4 fp32 cols at xc), p=0..3 ---
  const int xr   = tid >> 4;         // 0..31
  const int xc   = (tid & 15) * 4;   // 0..60
  const int cb   = xc >> 3;          // 16B col-block 0..7
  const int half = (xc >> 2) & 1;    // which 8B half of the block
  const float* xsrc[4];
  unsigned short* xdst[4];
#pragma unroll
  for (int p = 0; p < 4; ++p) {
    const int r = xr + p * 32;       // 0..127
    xsrc[p] = Xm + (size_t)(row_base + r) * 768 + xc;
    xdst[p] = &As[r * 64 + (cb ^ (r & 7)) * 8 + half * 4];
  }
  // --- W staging (global_load_lds w16: one issue = 8 rows x 128 B per wave) ---
  const int sr = lane >> 3;          // row-in-8
  const int ss = lane & 7;           // LDS slot this lane fills
  const unsigned short* wsrc[4];
#pragma unroll
  for (int p = 0; p < 4; ++p) {
    const int r = wave * 32 + p * 8 + sr;   // 0..255
    wsrc[p] = Wm + (size_t)(col_base + r) * 768 + (ss ^ (r & 7)) * 8;
  }

  // ---- prologue: issue W(0)->Ws[0], X(0)->xv, W(1)->Ws[1] ----
  float4 xv[4];
#pragma unroll
  for (int p = 0; p < 4; ++p) {
    __builtin_amdgcn_global_load_lds(
        (const __attribute__((address_space(1))) void*)wsrc[p],
        (__attribute__((address_space(3))) void*)&Ws[(wave * 32 + p * 8) * 64],
        16, 0, 0);
    wsrc[p] += 64;
  }
#pragma unroll
  for (int p = 0; p < 4; ++p) {
    xv[p] = *(const float4*)xsrc[p];
    xsrc[p] += 64;
  }
#pragma unroll
  for (int p = 0; p < 4; ++p) {
    __builtin_amdgcn_global_load_lds(
        (const __attribute__((address_space(1))) void*)wsrc[p],
        (__attribute__((address_space(3))) void*)&Ws[256 * 64 + (wave * 32 + p * 8) * 64],
        16, 0, 0);
    wsrc[p] += 64;
  }

  for (int kt = 0; kt < 12; ++kt) {
    const int boff = (kt & 1) * (256 * 64);

    // retire W(kt) + X(kt); keep W(kt+1) in flight across the barrier (T4)
    if (kt < 11) {
      asm volatile("s_waitcnt vmcnt(4)" ::: "memory");
    } else {
      asm volatile("s_waitcnt vmcnt(0)" ::: "memory");
    }

    // convert + write X(kt) into As (loads issued a full phase ago)
#pragma unroll
    for (int p = 0; p < 4; ++p) {
      const float4 v = xv[p];
      __hip_bfloat162 h0 = __float22bfloat162_rn(make_float2(v.x, v.y));
      __hip_bfloat162 h1 = __float22bfloat162_rn(make_float2(v.z, v.w));
      uint2 hv;
      hv.x = *(unsigned int*)&h0;
      hv.y = *(unsigned int*)&h1;
      *(uint2*)xdst[p] = hv;
    }

    // issue X(kt+1) -> regs (consumed at top of kt+1, hidden under compute)
    if (kt < 11) {
#pragma unroll
      for (int p = 0; p < 4; ++p) {
        xv[p] = *(const float4*)xsrc[p];
        xsrc[p] += 64;
      }
    }

    // barrier 1: As writes visible (lgkm drained), Ws[b] globally valid
    asm volatile("s_waitcnt lgkmcnt(0)" ::: "memory");
    __builtin_amdgcn_sched_barrier(0);
    __builtin_amdgcn_s_barrier();
    __builtin_amdgcn_sched_barrier(0);

    // compute(kt) on As / Ws[b]
    __builtin_amdgcn_s_setprio(1);
#pragma unroll
    for (int kk = 0; kk < 64; kk += 32) {
      const int kblk = (kk >> 3) + qd;           // 0..7
      const int slot = (kblk ^ (ln & 7)) * 8;
      bf16x8 a[4], b[4];
#pragma unroll
      for (int i = 0; i < 4; ++i)
        a[i] = *(const bf16x8*)(&As[(wm * 64 + i * 16 + ln) * 64 + slot]);
#pragma unroll
      for (int j = 0; j < 4; ++j)
        b[j] = *(const bf16x8*)(&Ws[boff + (wn * 64 + j * 16 + ln) * 64 + slot]);
#pragma unroll
      for (int i = 0; i < 4; ++i)
#pragma unroll
        for (int j = 0; j < 4; ++j)
          acc[i][j] = __builtin_amdgcn_mfma_f32_16x16x32_bf16(a[i], b[j], acc[i][j], 0, 0, 0);
    }
    __builtin_amdgcn_s_setprio(0);

    // barrier 2: every wave done reading Ws[b] / As -> safe to re-stage
    __builtin_amdgcn_sched_barrier(0);
    __builtin_amdgcn_s_barrier();
    __builtin_amdgcn_sched_barrier(0);

    // issue W(kt+2) -> Ws[b] (buffer compute(kt) just vacated); in flight
    // through all of iter kt+1, waited at top of iter kt+2.
    if (kt < 10) {
#pragma unroll
      for (int p = 0; p < 4; ++p) {
        __builtin_amdgcn_global_load_lds(
            (const __attribute__((address_space(1))) void*)wsrc[p],
            (__attribute__((address_space(3))) void*)&Ws[boff + (wave * 32 + p * 8) * 64],
            16, 0, 0);
        wsrc[p] += 64;
      }
    }
  }

  float* Om = out + (size_t)m * 8192 * 768;
#pragma unroll
  for (int j = 0; j < 4; ++j) {
    const int o = col_base + wn * 64 + j * 16 + ln;
    const float bias = bp[o];
#pragma unroll
    for (int i = 0; i < 4; ++i) {
      const int R = row_base + wm * 64 + i * 16 + qd * 4;
      float* dst = Om + (size_t)R * 768 + o;
#pragma unroll
      for (int v = 0; v < 4; ++v)
        dst[(size_t)v * 768] = acc[i][j][v] + bias;
    }
  }
}

extern "C" void kernel_launch(void* const* d_in, const int* in_sizes, int n_in,
                              void* d_out, int out_size, void* d_ws, size_t ws_size,
                              hipStream_t stream) {
  const float* x  = (const float*)d_in[0];   // [32, 1024, 768]
  const float* Wp = (const float*)d_in[1];   // [768, 768]
  const float* bp = (const float*)d_in[2];   // [768]
  const float* A  = (const float*)d_in[3];   // [4, 16, 768]
  const float* Bw = (const float*)d_in[4];   // [4, 768, 16]
  float* out = (float*)d_out;                // [32, 1024, 768]

  unsigned short* Weff = (unsigned short*)d_ws;  // [4][768][768] bf16 = 4.5 MB

  weff_fast<<<dim3(3, 48, 4), 256, 0, stream>>>(Wp, A, Bw, Weff);
  lora_gemm_fused<<<dim3(768), 512, 0, stream>>>(x, Weff, bp, out);
}